// Round 3
// baseline (780.469 us; speedup 1.0000x reference)
//
#include <hip/hip_runtime.h>
#include <math.h>

// Problem constants (B=4, S=4096, D=2048, E=64, K=2)
#define BS_TOT 16384
#define DDIM   2048
#define NEXP   64
#define TOPK   2

#define NWAVES  8                 // waves per block = intra-block D-split
#define RPB     32                // rows per block (shared by all 8 waves)
#define DSLICE  (DDIM / NWAVES)   // 256 d per wave
#define TD      32                // d-tile staged per round
#define NTILE   (DSLICE / TD)     // 8 tiles per wave

// lane = expert. Wave wv computes acc[32 rows] over d in [wv*256, wv*256+256),
// x staged in a per-wave-private LDS tile (coalesced float4 global loads ->
// ds_write_b128 -> wave-uniform ds_read_b128 broadcast), W read per-lane
// (coalesced 256B/d, L2-resident; 256 MB total L2 traffic). Cross-wave reduce
// via LDS float atomics, then per-row full-wave softmax + stable top-2.
__global__ __launch_bounds__(512, 4)
void router_kernel(const float* __restrict__ x, const float* __restrict__ W,
                   const float* __restrict__ bias, const float* __restrict__ noise,
                   float* __restrict__ out)
{
    __shared__ float xt[NWAVES][RPB][TD];   // 32 KB: per-wave x tiles
    __shared__ float lacc[RPB][NEXP];       // 8 KB: cross-wave reduction

    const int tid  = threadIdx.x;
    const int lane = tid & 63;
    const int wv   = __builtin_amdgcn_readfirstlane(tid >> 6);  // uniform wave id
    const int row0 = blockIdx.x * RPB;

    for (int i = tid; i < RPB * NEXP; i += 512) ((float*)lacc)[i] = 0.0f;
    __syncthreads();

    float acc[RPB];
#pragma unroll
    for (int r = 0; r < RPB; ++r) acc[r] = 0.0f;

    const int dw0  = wv * DSLICE;
    // staging map: round k (0..3): row = 8k + (lane>>3), d-quad = lane&7
    // -> each 8-lane group reads 128 B contiguous of one row. Coalesced.
    const int srow = lane >> 3;
    const int sdq  = (lane & 7) * 4;

    const float* xg = x + (size_t)(row0 + srow) * DDIM + dw0 + sdq;
    float*       xl = &xt[wv][srow][sdq];

    float4 g[4];
#pragma unroll
    for (int k = 0; k < 4; ++k)
        g[k] = *(const float4*)(xg + (size_t)(8 * k) * DDIM);

#pragma unroll 1
    for (int t = 0; t < NTILE; ++t) {
        // stage tile t (per-wave private region: no __syncthreads needed;
        // program order protects write-after-read vs previous tile's compute)
#pragma unroll
        for (int k = 0; k < 4; ++k)
            *(float4*)(xl + 8 * k * TD) = g[k];

        // prefetch tile t+1 global loads; they fly during tile-t compute
        if (t + 1 < NTILE) {
#pragma unroll
            for (int k = 0; k < 4; ++k)
                g[k] = *(const float4*)(xg + (size_t)(8 * k) * DDIM + (t + 1) * TD);
        }

        const float* wp = W + (size_t)(dw0 + t * TD) * NEXP + lane;
#pragma unroll
        for (int q = 0; q < TD / 4; ++q) {
            const float w0 = wp[(q * 4 + 0) * NEXP];
            const float w1 = wp[(q * 4 + 1) * NEXP];
            const float w2 = wp[(q * 4 + 2) * NEXP];
            const float w3 = wp[(q * 4 + 3) * NEXP];
#pragma unroll
            for (int r = 0; r < RPB; ++r) {
                const float4 xv = *(const float4*)&xt[wv][r][q * 4];  // broadcast
                acc[r] = fmaf(xv.x, w0, acc[r]);
                acc[r] = fmaf(xv.y, w1, acc[r]);
                acc[r] = fmaf(xv.z, w2, acc[r]);
                acc[r] = fmaf(xv.w, w3, acc[r]);
            }
        }
    }

    // cross-wave reduce (ds_add_f32; consecutive lanes -> consecutive banks)
#pragma unroll
    for (int r = 0; r < RPB; ++r) atomicAdd(&lacc[r][lane], acc[r]);
    __syncthreads();

    // ---------------- epilogue: 4 rows per wave, all cross-lane ----------
    const float blane = bias[lane];
    float* const scores_out = out + 2 * BS_TOT * TOPK;
    float* const iout       = out + BS_TOT * TOPK;

#pragma unroll
    for (int j = 0; j < RPB / NWAVES; ++j) {
        const int rl  = wv * (RPB / NWAVES) + j;
        const int row = row0 + rl;
        const float v = lacc[rl][lane] + blane + 0.1f * noise[(size_t)row * NEXP + lane];

        float m = v;
#pragma unroll
        for (int off = 1; off < 64; off <<= 1) m = fmaxf(m, __shfl_xor(m, off));
        const float p = __expf(v - m);
        float s = p;
#pragma unroll
        for (int off = 1; off < 64; off <<= 1) s += __shfl_xor(s, off);
        const float sc = p * (1.0f / s);

        scores_out[(size_t)row * NEXP + lane] = sc;   // 256B coalesced

        // top-2 across 64 lanes on logits (order-identical to scores),
        // ties -> lower index (matches jax.lax.top_k).
        float a1 = v, a2 = -INFINITY;
        int   i1 = lane, i2 = 0x7fffffff;
#pragma unroll
        for (int off = 1; off < 64; off <<= 1) {
            const float o1 = __shfl_xor(a1, off), o2 = __shfl_xor(a2, off);
            const int  oi1 = __shfl_xor(i1, off), oi2 = __shfl_xor(i2, off);
            if (o1 > a1 || (o1 == a1 && oi1 < i1)) {
                if (a1 > o2 || (a1 == o2 && i1 < oi2)) { a2 = a1; i2 = i1; }
                else                                   { a2 = o2; i2 = oi2; }
                a1 = o1; i1 = oi1;
            } else {
                if (o1 > a2 || (o1 == a2 && oi1 < i2)) { a2 = o1; i2 = oi1; }
            }
        }
        const float s1 = __shfl(sc, i1);   // bitwise == scores entries
        const float s2 = __shfl(sc, i2);
        if (lane == 0) {
            out[(size_t)row * TOPK + 0]  = s1;
            out[(size_t)row * TOPK + 1]  = s2;
            iout[(size_t)row * TOPK + 0] = (float)i1;
            iout[(size_t)row * TOPK + 1] = (float)i2;
        }
    }
}

extern "C" void kernel_launch(void* const* d_in, const int* in_sizes, int n_in,
                              void* d_out, int out_size, void* d_ws, size_t ws_size,
                              hipStream_t stream)
{
    const float* x     = (const float*)d_in[0];
    const float* W     = (const float*)d_in[1];
    const float* bias  = (const float*)d_in[2];
    const float* noise = (const float*)d_in[3];
    float* out = (float*)d_out;
    (void)in_sizes; (void)n_in; (void)out_size; (void)d_ws; (void)ws_size;

    hipLaunchKernelGGL(router_kernel, dim3(BS_TOT / RPB), dim3(512), 0, stream,
                       x, W, bias, noise, out);
}

// Round 4
// 325.918 us; speedup vs baseline: 2.3947x; 2.3947x over previous
//
#include <hip/hip_runtime.h>
#include <math.h>

// Problem constants (B=4, S=4096, D=2048, E=64, K=2)
#define BS_TOT 16384
#define DDIM   2048
#define NEXP   64
#define TOPK   2

#define NW   16            // waves per block (D-split)
#define RPB  64            // rows per block = lanes
#define DS   (DDIM / NW)   // 128 d per wave

// lane = row. Each wave covers a 128-wide D-slice for the block's 64 rows:
//   per d: W[d][0..63] via the SCALAR pipe (readfirstlane-uniform pointer ->
//   s_load_dwordx16, SGPR-resident; proven scalarization pattern from R1),
//   x[row][d] per-lane (float4 per 4 d, 64B-line reuse x4 from L1),
//   64 v_fmac_f32 (SGPR operand) into acc[64] VGPRs.
// 64 FMAs (128 cyc) per scalar-load stall (~200 cyc) * 4 waves/SIMD -> VALU
// saturated. launch_bounds(1024,2): VGPR cap 256, acc[64]+misc fits, NO SPILL.
// Cross-wave reduce: LDS f32 atomics into lacc[64][65] (padded: bank = lane+e,
// conflict-free). Epilogue: full-wave softmax + stable top-2 per row (R1-proven).
__global__ __launch_bounds__(1024, 2)
void router_kernel(const float* __restrict__ x, const float* __restrict__ W,
                   const float* __restrict__ bias, const float* __restrict__ noise,
                   float* __restrict__ out)
{
    __shared__ float lacc[RPB][NEXP + 1];   // 16.25 KB, +1 pad

    const int tid  = threadIdx.x;
    const int lane = tid & 63;                                   // local row
    const int wv   = __builtin_amdgcn_readfirstlane(tid >> 6);   // uniform wave id
    const int row0 = blockIdx.x * RPB;
    const int row  = row0 + lane;

    for (int i = tid; i < RPB * (NEXP + 1); i += 1024) ((float*)lacc)[i] = 0.0f;
    __syncthreads();

    float acc[NEXP];
#pragma unroll
    for (int e = 0; e < NEXP; ++e) acc[e] = 0.0f;

    const int d0 = wv * DS;
    const float* xp = x + (size_t)row * DDIM + d0;   // per-lane
    const float* Wp = W + (size_t)d0 * NEXP;         // wave-uniform -> s_load

#pragma unroll 1
    for (int dd = 0; dd < DS; dd += 4) {
        const float4 xv = *(const float4*)(xp + dd);
        const float* wr = Wp + (size_t)dd * NEXP;
#pragma unroll
        for (int e = 0; e < NEXP; ++e) acc[e] = fmaf(xv.x, wr[e],            acc[e]);
#pragma unroll
        for (int e = 0; e < NEXP; ++e) acc[e] = fmaf(xv.y, wr[NEXP + e],     acc[e]);
#pragma unroll
        for (int e = 0; e < NEXP; ++e) acc[e] = fmaf(xv.z, wr[2 * NEXP + e], acc[e]);
#pragma unroll
        for (int e = 0; e < NEXP; ++e) acc[e] = fmaf(xv.w, wr[3 * NEXP + e], acc[e]);
    }

    // cross-wave reduce: bank(lacc[lane][e]) = (lane*65+e)%32 -> lane-consecutive
#pragma unroll
    for (int e = 0; e < NEXP; ++e) atomicAdd(&lacc[lane][e], acc[e]);
    __syncthreads();

    // ---------------- epilogue: 4 rows per wave, all cross-lane ------------
    const float blane = bias[lane];
    float* const scores_out = out + 2 * BS_TOT * TOPK;
    float* const iout       = out + BS_TOT * TOPK;

#pragma unroll
    for (int j = 0; j < RPB / NW; ++j) {
        const int rl  = wv * (RPB / NW) + j;
        const int r2  = row0 + rl;
        const float v = lacc[rl][lane] + blane + 0.1f * noise[(size_t)r2 * NEXP + lane];

        float m = v;
#pragma unroll
        for (int off = 1; off < 64; off <<= 1) m = fmaxf(m, __shfl_xor(m, off));
        const float p = __expf(v - m);
        float s = p;
#pragma unroll
        for (int off = 1; off < 64; off <<= 1) s += __shfl_xor(s, off);
        const float sc = p * (1.0f / s);

        scores_out[(size_t)r2 * NEXP + lane] = sc;   // 256B coalesced

        // top-2 across 64 lanes on logits (order-identical to scores),
        // ties -> lower index (matches jax.lax.top_k).
        float a1 = v, a2 = -INFINITY;
        int   i1 = lane, i2 = 0x7fffffff;
#pragma unroll
        for (int off = 1; off < 64; off <<= 1) {
            const float o1 = __shfl_xor(a1, off), o2 = __shfl_xor(a2, off);
            const int  oi1 = __shfl_xor(i1, off), oi2 = __shfl_xor(i2, off);
            if (o1 > a1 || (o1 == a1 && oi1 < i1)) {
                if (a1 > o2 || (a1 == o2 && i1 < oi2)) { a2 = a1; i2 = i1; }
                else                                   { a2 = o2; i2 = oi2; }
                a1 = o1; i1 = oi1;
            } else {
                if (o1 > a2 || (o1 == a2 && oi1 < i2)) { a2 = o1; i2 = oi1; }
            }
        }
        const float s1 = __shfl(sc, i1);   // bitwise == scores entries
        const float s2 = __shfl(sc, i2);
        if (lane == 0) {
            out[(size_t)r2 * TOPK + 0]  = s1;
            out[(size_t)r2 * TOPK + 1]  = s2;
            iout[(size_t)r2 * TOPK + 0] = (float)i1;
            iout[(size_t)r2 * TOPK + 1] = (float)i2;
        }
    }
}

extern "C" void kernel_launch(void* const* d_in, const int* in_sizes, int n_in,
                              void* d_out, int out_size, void* d_ws, size_t ws_size,
                              hipStream_t stream)
{
    const float* x     = (const float*)d_in[0];
    const float* W     = (const float*)d_in[1];
    const float* bias  = (const float*)d_in[2];
    const float* noise = (const float*)d_in[3];
    float* out = (float*)d_out;
    (void)in_sizes; (void)n_in; (void)out_size; (void)d_ws; (void)ws_size;

    hipLaunchKernelGGL(router_kernel, dim3(BS_TOT / RPB), dim3(1024), 0, stream,
                       x, W, bias, noise, out);
}

// Round 5
// 312.061 us; speedup vs baseline: 2.5010x; 1.0444x over previous
//
#include <hip/hip_runtime.h>
#include <math.h>

// Problem constants (B=4, S=4096, D=2048, E=64, K=2)
#define BS_TOT 16384
#define DDIM   2048
#define NEXP   64
#define TOPK   2

#define NW     16               // waves per block (D-split)
#define RPB    64               // rows per block
#define DSLICE (DDIM / NW)      // 128 d per wave
#define TK     8                // d per staged tile
#define NTILE  (DSLICE / TK)    // 16 tiles

// Register-blocked LDS GEMM (m97 structure, VALU FMA):
//   lane = (rg=lane>>3 row-group, er=lane&7 expert-group), 8x8 acc block.
//   Per d: 4 ds_read_b128 (8 x + 8 w) -> 64 v_fmac_f32. 1 B/FMA balances
//   LDS 128 B/cyc vs VALU 128 FMA/cyc.
//   Wave-private tiles (no K-loop barriers; DS is in-order per wave).
//   x transposed on store (xT[k][row]); W tile stored direct ([k][e]).
//   Global prefetch: tile compute (8d*64fma = 1024 cyc) covers HBM ~900 cyc.
// 1024 thr = 16 waves => hard VGPR cap 128; est live ~110 (acc64+frag16+pf16).
__global__ __launch_bounds__(1024)
void router_kernel(const float* __restrict__ x, const float* __restrict__ W,
                   const float* __restrict__ bias, const float* __restrict__ noise,
                   float* __restrict__ out)
{
    __shared__ float smem[NW][2][TK][NEXP];          // 64 KB: [wave][xT|W][k][64]
    float (*lacc)[NEXP + 1] = (float (*)[NEXP + 1])smem;  // 16.6 KB aliased (post-loop)

    const int tid  = threadIdx.x;
    const int lane = tid & 63;
    const int wv   = __builtin_amdgcn_readfirstlane(tid >> 6);  // 0..15
    const int row0 = blockIdx.x * RPB;
    const int rg   = lane >> 3;        // row group   (8 rows  rg*8..rg*8+7)
    const int er   = lane & 7;         // expert group (8 exps er*8..er*8+7)

    float acc[8][8];
#pragma unroll
    for (int i = 0; i < 8; ++i)
#pragma unroll
        for (int j = 0; j < 8; ++j) acc[i][j] = 0.0f;

    const int dw0 = wv * DSLICE;
    // staging maps (per wave): x: lane = row, 8 d per tile (2 float4).
    //                          W: lane -> (k=lane>>3, e8=(lane&7)*8), 2 float4.
    const float* xg = x + (size_t)(row0 + lane) * DDIM + dw0;
    const int    wk = lane >> 3;
    const int    we = (lane & 7) * 8;
    const float* wg = W + (size_t)(dw0 + wk) * NEXP + we;

    float4 gx0 = *(const float4*)(xg);
    float4 gx1 = *(const float4*)(xg + 4);
    float4 gw0 = *(const float4*)(wg);
    float4 gw1 = *(const float4*)(wg + 4);

#pragma unroll 1
    for (int t = 0; t < NTILE; ++t) {
        // stage tile t (wave-private region: DS in-order per wave, no barrier)
        smem[wv][0][0][lane] = gx0.x;   // xT[k][row] transpose-on-store
        smem[wv][0][1][lane] = gx0.y;
        smem[wv][0][2][lane] = gx0.z;
        smem[wv][0][3][lane] = gx0.w;
        smem[wv][0][4][lane] = gx1.x;
        smem[wv][0][5][lane] = gx1.y;
        smem[wv][0][6][lane] = gx1.z;
        smem[wv][0][7][lane] = gx1.w;
        *(float4*)&smem[wv][1][wk][we]     = gw0;
        *(float4*)&smem[wv][1][wk][we + 4] = gw1;

        // prefetch tile t+1 (in flight during tile-t compute)
        if (t + 1 < NTILE) {
            const float* xn = xg + (t + 1) * TK;
            gx0 = *(const float4*)(xn);
            gx1 = *(const float4*)(xn + 4);
            const float* wn = wg + (size_t)(t + 1) * TK * NEXP;
            gw0 = *(const float4*)(wn);
            gw1 = *(const float4*)(wn + 4);
        }

#pragma unroll 1
        for (int k = 0; k < TK; ++k) {
            const float4 a0 = *(const float4*)&smem[wv][0][k][rg * 8];
            const float4 a1 = *(const float4*)&smem[wv][0][k][rg * 8 + 4];
            const float4 b0 = *(const float4*)&smem[wv][1][k][er * 8];
            const float4 b1 = *(const float4*)&smem[wv][1][k][er * 8 + 4];
            const float av[8] = {a0.x, a0.y, a0.z, a0.w, a1.x, a1.y, a1.z, a1.w};
            const float bv[8] = {b0.x, b0.y, b0.z, b0.w, b1.x, b1.y, b1.z, b1.w};
#pragma unroll
            for (int i = 0; i < 8; ++i)
#pragma unroll
                for (int j = 0; j < 8; ++j)
                    acc[i][j] = fmaf(av[i], bv[j], acc[i][j]);
        }
    }

    // -------- cross-wave reduce (lacc aliases tile memory; barrier first) ----
    __syncthreads();
    for (int i = tid; i < RPB * (NEXP + 1); i += 1024) ((float*)lacc)[i] = 0.0f;
    __syncthreads();
#pragma unroll
    for (int i = 0; i < 8; ++i)
#pragma unroll
        for (int j = 0; j < 8; ++j)
            atomicAdd(&lacc[rg * 8 + i][er * 8 + j], acc[i][j]);
    __syncthreads();

    // ---------------- epilogue: 4 rows per wave, all cross-lane ------------
    const float blane = bias[lane];
    float* const scores_out = out + 2 * BS_TOT * TOPK;
    float* const iout       = out + BS_TOT * TOPK;

#pragma unroll
    for (int j = 0; j < RPB / NW; ++j) {
        const int rl  = wv * (RPB / NW) + j;
        const int r2  = row0 + rl;
        const float v = lacc[rl][lane] + blane + 0.1f * noise[(size_t)r2 * NEXP + lane];

        float m = v;
#pragma unroll
        for (int off = 1; off < 64; off <<= 1) m = fmaxf(m, __shfl_xor(m, off));
        const float p = __expf(v - m);
        float s = p;
#pragma unroll
        for (int off = 1; off < 64; off <<= 1) s += __shfl_xor(s, off);
        const float sc = p * (1.0f / s);

        scores_out[(size_t)r2 * NEXP + lane] = sc;   // 256B coalesced

        // top-2 across 64 lanes on logits (order-identical to scores),
        // ties -> lower index (matches jax.lax.top_k).
        float a1 = v, a2 = -INFINITY;
        int   i1 = lane, i2 = 0x7fffffff;
#pragma unroll
        for (int off = 1; off < 64; off <<= 1) {
            const float o1 = __shfl_xor(a1, off), o2 = __shfl_xor(a2, off);
            const int  oi1 = __shfl_xor(i1, off), oi2 = __shfl_xor(i2, off);
            if (o1 > a1 || (o1 == a1 && oi1 < i1)) {
                if (a1 > o2 || (a1 == o2 && i1 < oi2)) { a2 = a1; i2 = i1; }
                else                                   { a2 = o2; i2 = oi2; }
                a1 = o1; i1 = oi1;
            } else {
                if (o1 > a2 || (o1 == a2 && oi1 < i2)) { a2 = o1; i2 = oi1; }
            }
        }
        const float s1 = __shfl(sc, i1);   // bitwise == scores entries
        const float s2 = __shfl(sc, i2);
        if (lane == 0) {
            out[(size_t)r2 * TOPK + 0]  = s1;
            out[(size_t)r2 * TOPK + 1]  = s2;
            iout[(size_t)r2 * TOPK + 0] = (float)i1;
            iout[(size_t)r2 * TOPK + 1] = (float)i2;
        }
    }
}

extern "C" void kernel_launch(void* const* d_in, const int* in_sizes, int n_in,
                              void* d_out, int out_size, void* d_ws, size_t ws_size,
                              hipStream_t stream)
{
    const float* x     = (const float*)d_in[0];
    const float* W     = (const float*)d_in[1];
    const float* bias  = (const float*)d_in[2];
    const float* noise = (const float*)d_in[3];
    float* out = (float*)d_out;
    (void)in_sizes; (void)n_in; (void)out_size; (void)d_ws; (void)ws_size;

    hipLaunchKernelGGL(router_kernel, dim3(BS_TOT / RPB), dim3(1024), 0, stream,
                       x, W, bias, noise, out);
}

// Round 6
// 305.555 us; speedup vs baseline: 2.5543x; 1.0213x over previous
//
#include <hip/hip_runtime.h>
#include <math.h>

// Problem constants (B=4, S=4096, D=2048, E=64, K=2)
#define BS_TOT 16384
#define DDIM   2048
#define NEXP   64
#define TOPK   2

#define NW     16               // waves per block (D-split)
#define RPB    64               // rows per block
#define DSLICE (DDIM / NW)      // 128 d per wave
#define TK     16               // d per staged tile
#define NTILE  (DSLICE / TK)    // 8 tiles

// 8x8 register-block outer product, operand pipeline fixed:
//  - x: per-lane 64B/tile global loads (full line) -> regs -> transpose-store
//    xT[k][row] (2-way banks, b128-readable). Wave-private, DS in-order: no waits.
//  - W: async global->LDS (global_load_lds width16) into wt[k][e]; one
//    vmcnt(0) per tile, issued right after previous tile's reads complete.
//  - k-loop unroll 4: 16 b128 reads batched per 256-FMA run; compiler emits
//    fine-grained lgkmcnt.
// acc[8][8] -> AGPRs (proven R4). 16 waves/block, 1 block/CU, 4 waves/SIMD.

__device__ __forceinline__ void gload_lds16(const float* g, float* l) {
    __builtin_amdgcn_global_load_lds(
        (const __attribute__((address_space(1))) unsigned int*)(g),
        (__attribute__((address_space(3))) unsigned int*)(l), 16, 0, 0);
}

__global__ __launch_bounds__(1024)
void router_kernel(const float* __restrict__ x, const float* __restrict__ W,
                   const float* __restrict__ bias, const float* __restrict__ noise,
                   float* __restrict__ out)
{
    __shared__ float smem[NW][2048];                      // 128 KB: per wave xT|wt
    float (*lacc)[NEXP + 1] = (float (*)[NEXP + 1])smem;  // aliased post-loop

    const int tid  = threadIdx.x;
    const int lane = tid & 63;
    const int wv   = __builtin_amdgcn_readfirstlane(tid >> 6);  // 0..15
    const int row0 = blockIdx.x * RPB;
    const int rg   = lane >> 3;        // row group
    const int er   = lane & 7;         // expert group

    float* const xt = &smem[wv][0];     // xT[16][64]
    float* const wt = &smem[wv][1024];  // wt[16][64]

    float acc[8][8];
#pragma unroll
    for (int i = 0; i < 8; ++i)
#pragma unroll
        for (int j = 0; j < 8; ++j) acc[i][j] = 0.0f;

    const int dw0 = wv * DSLICE;
    const float* xg = x + (size_t)(row0 + lane) * DDIM + dw0;  // per-lane row
    // W stage map, instr i: lane -> k=4i+(lane>>4), col=(lane&15)*4; dest lane*16B
    const int wkk = lane >> 4;
    const int wcc = (lane & 15) * 4;

    // prologue: x tile0 -> regs; W tile0 -> LDS (async)
    float4 gx[4];
#pragma unroll
    for (int q = 0; q < 4; ++q) gx[q] = *(const float4*)(xg + q * 4);
#pragma unroll
    for (int i = 0; i < 4; ++i)
        gload_lds16(W + (size_t)(dw0 + 4 * i + wkk) * NEXP + wcc, wt + i * 256);

#pragma unroll 1
    for (int t = 0; t < NTILE; ++t) {
        // stage x tile t (transpose-on-store; wave-private, no barrier)
#pragma unroll
        for (int q = 0; q < 4; ++q) {
            xt[(q * 4 + 0) * 64 + lane] = gx[q].x;
            xt[(q * 4 + 1) * 64 + lane] = gx[q].y;
            xt[(q * 4 + 2) * 64 + lane] = gx[q].z;
            xt[(q * 4 + 3) * 64 + lane] = gx[q].w;
        }
        __builtin_amdgcn_s_waitcnt(0x0F70);   // vmcnt(0): W tile t landed
        // prefetch x tile t+1 (flies under the k-loop)
        if (t + 1 < NTILE) {
            const float* xn = xg + (t + 1) * TK;
#pragma unroll
            for (int q = 0; q < 4; ++q) gx[q] = *(const float4*)(xn + q * 4);
        }

#pragma unroll 4
        for (int k = 0; k < TK; ++k) {
            const float4 a0 = *(const float4*)&xt[k * 64 + rg * 8];
            const float4 a1 = *(const float4*)&xt[k * 64 + rg * 8 + 4];
            const float4 b0 = *(const float4*)&wt[k * 64 + er * 8];
            const float4 b1 = *(const float4*)&wt[k * 64 + er * 8 + 4];
            const float av[8] = {a0.x, a0.y, a0.z, a0.w, a1.x, a1.y, a1.z, a1.w};
            const float bv[8] = {b0.x, b0.y, b0.z, b0.w, b1.x, b1.y, b1.z, b1.w};
#pragma unroll
            for (int i = 0; i < 8; ++i)
#pragma unroll
                for (int j = 0; j < 8; ++j)
                    acc[i][j] = fmaf(av[i], bv[j], acc[i][j]);
        }

        __builtin_amdgcn_s_waitcnt(0xC07F);   // lgkmcnt(0): wt reads all executed
        if (t + 1 < NTILE) {                  // async W tile t+1
            const float* wn = W + (size_t)(dw0 + (t + 1) * TK) * NEXP;
#pragma unroll
            for (int i = 0; i < 4; ++i)
                gload_lds16(wn + (size_t)(4 * i + wkk) * NEXP + wcc, wt + i * 256);
        }
    }

    // -------- cross-wave reduce (lacc aliases tiles; fence first) ----------
    __syncthreads();
    for (int i = tid; i < RPB * (NEXP + 1); i += 1024) ((float*)lacc)[i] = 0.0f;
    __syncthreads();
#pragma unroll
    for (int i = 0; i < 8; ++i)
#pragma unroll
        for (int j = 0; j < 8; ++j)
            atomicAdd(&lacc[rg * 8 + i][er * 8 + j], acc[i][j]);
    __syncthreads();

    // ---------------- epilogue: 4 rows per wave, all cross-lane ------------
    const float blane = bias[lane];
    float* const scores_out = out + 2 * BS_TOT * TOPK;
    float* const iout       = out + BS_TOT * TOPK;

#pragma unroll
    for (int j = 0; j < RPB / NW; ++j) {
        const int rl  = wv * (RPB / NW) + j;
        const int r2  = row0 + rl;
        const float v = lacc[rl][lane] + blane + 0.1f * noise[(size_t)r2 * NEXP + lane];

        float m = v;
#pragma unroll
        for (int off = 1; off < 64; off <<= 1) m = fmaxf(m, __shfl_xor(m, off));
        const float p = __expf(v - m);
        float s = p;
#pragma unroll
        for (int off = 1; off < 64; off <<= 1) s += __shfl_xor(s, off);
        const float sc = p * (1.0f / s);

        scores_out[(size_t)r2 * NEXP + lane] = sc;   // 256B coalesced

        // top-2 across 64 lanes on logits (order-identical to scores),
        // ties -> lower index (matches jax.lax.top_k).
        float a1 = v, a2 = -INFINITY;
        int   i1 = lane, i2 = 0x7fffffff;
#pragma unroll
        for (int off = 1; off < 64; off <<= 1) {
            const float o1 = __shfl_xor(a1, off), o2 = __shfl_xor(a2, off);
            const int  oi1 = __shfl_xor(i1, off), oi2 = __shfl_xor(i2, off);
            if (o1 > a1 || (o1 == a1 && oi1 < i1)) {
                if (a1 > o2 || (a1 == o2 && i1 < oi2)) { a2 = a1; i2 = i1; }
                else                                   { a2 = o2; i2 = oi2; }
                a1 = o1; i1 = oi1;
            } else {
                if (o1 > a2 || (o1 == a2 && oi1 < i2)) { a2 = o1; i2 = oi1; }
            }
        }
        const float s1 = __shfl(sc, i1);   // bitwise == scores entries
        const float s2 = __shfl(sc, i2);
        if (lane == 0) {
            out[(size_t)r2 * TOPK + 0]  = s1;
            out[(size_t)r2 * TOPK + 1]  = s2;
            iout[(size_t)r2 * TOPK + 0] = (float)i1;
            iout[(size_t)r2 * TOPK + 1] = (float)i2;
        }
    }
}

extern "C" void kernel_launch(void* const* d_in, const int* in_sizes, int n_in,
                              void* d_out, int out_size, void* d_ws, size_t ws_size,
                              hipStream_t stream)
{
    const float* x     = (const float*)d_in[0];
    const float* W     = (const float*)d_in[1];
    const float* bias  = (const float*)d_in[2];
    const float* noise = (const float*)d_in[3];
    float* out = (float*)d_out;
    (void)in_sizes; (void)n_in; (void)out_size; (void)d_ws; (void)ws_size;

    hipLaunchKernelGGL(router_kernel, dim3(BS_TOT / RPB), dim3(1024), 0, stream,
                       x, W, bias, noise, out);
}